// Round 1
// baseline (11967.953 us; speedup 1.0000x reference)
//
#include <hip/hip_runtime.h>

// DeepHandwritingPredictionModel: 3-layer peephole LSTM (B=64,T=800,U=400) + MDN(M=20)
// Strategy: per-layer persistent scan kernel, 4 batch-groups x 20 unit-slices.
// Weights register-resident (bf16 fragments); h exchanged cross-slice per step via
// global ring + agent-scope flag counters. MDN = small MFMA GEMM + transforms.

#define TSTEPS 800
#define NGROUP 4
#define GB 16          // batches per group
#define NSLICE 20      // column slices per layer
#define US 20          // units per slice
#define CS 80          // interleaved cols per slice (4 gates * US)
#define KPAD 832       // padded K for scan (h 400 | hprev 400 | x 3 | one 1 -> 832)
#define MK 416         // padded K for MDN (h 400 | one 1 -> 416)

typedef __attribute__((ext_vector_type(8))) __bf16 bf16x8;
typedef __attribute__((ext_vector_type(4))) float floatx4;

__device__ __forceinline__ unsigned short f2bf(float f) {
    unsigned int u = __float_as_uint(f);
    return (unsigned short)((u + 0x7FFFu + ((u >> 16) & 1u)) >> 16);
}
__device__ __forceinline__ float sigm_(float v) { return 1.f / (1.f + __expf(-v)); }
__device__ __forceinline__ float tanh_(float v) { float e = __expf(2.f * v); return 1.f - 2.f / (e + 1.f); }

// Pack per-layer weights into gate-interleaved, column-major-by-K bf16:
// dst[col][k], col = 4*u + gate (gate 0..3 = i,f,c,o), orig col co = gate*400+u.
// k<400: Wh rows; [400,800): Wx h_prev rows (layers 1,2); x rows; bias row; zeros.
__global__ void pack_scan(const float* __restrict__ Wx, const float* __restrict__ Wh,
                          const float* __restrict__ bias, unsigned short* __restrict__ dst,
                          int has_prev) {
    int idx = blockIdx.x * 256 + threadIdx.x;
    if (idx >= 1600 * KPAD) return;
    int col = idx / KPAD;
    int k = idx - col * KPAD;
    int u = col >> 2, gs = col & 3;
    int co = gs * 400 + u;
    float v = 0.f;
    if (k < 400) v = Wh[k * 1600 + co];
    else if (has_prev) {
        if (k < 800) v = Wx[(3 + k - 400) * 1600 + co];
        else if (k < 803) v = Wx[(k - 800) * 1600 + co];
        else if (k == 803) v = bias[co];
    } else {
        if (k < 403) v = Wx[(k - 400) * 1600 + co];
        else if (k == 403) v = bias[co];
    }
    dst[idx] = f2bf(v);
}

__global__ void pack_mdn(const float* __restrict__ Wm, const float* __restrict__ bm,
                         unsigned short* __restrict__ dst) {
    int idx = blockIdx.x * 256 + threadIdx.x;
    if (idx >= 128 * MK) return;
    int col = idx / MK, k = idx - col * MK;
    float v = 0.f;
    if (col < 121) {
        if (k < 400) v = Wm[k * 121 + col];
        else if (k == 400) v = bm[col];
    }
    dst[idx] = f2bf(v);
}

// Persistent scan over T steps. Grid = NGROUP*NSLICE blocks, 320 threads (5 waves).
// Wave w owns 16-col N-tile w of this block's 80-col slice; its B fragments live in
// VGPRs for the whole kernel. A = [h(t-1)|hprev(t)|x(t)|1] staged in LDS each step.
template<int KT, int HASP>
__global__ __launch_bounds__(320)
void scan_layer(const unsigned short* __restrict__ Bp,
                const float* __restrict__ x,
                const unsigned short* __restrict__ hprev,   // [T][64][400] bf16 (or null)
                unsigned short* __restrict__ hall,          // [T][64][400] bf16 out
                unsigned short* __restrict__ hbuf,          // [NGROUP][2][GB][400] bf16 ring
                int* __restrict__ flags,                    // [NGROUP][T]
                const float* __restrict__ peepi,
                const float* __restrict__ peepf,
                const float* __restrict__ peepo) {
    constexpr int XOFF = HASP ? 800 : 400;   // x cols start; "+3" is the ones col
    const int g = blockIdx.x / NSLICE;
    const int s = blockIdx.x - g * NSLICE;
    const int tid = threadIdx.x;
    const int lane = tid & 63;
    const int w = tid >> 6;

    __shared__ unsigned short A[16 * 840];   // 16 batches x KPAD (pad 840 => 2-way banks)
    __shared__ float Z[16 * 84];             // z slice, fp32

    unsigned short* hb = hbuf + g * (2 * GB * 400);
    int* flag = flags + g * TSTEPS;

    for (int i = tid; i < 16 * 840; i += 320) A[i] = 0;
    __syncthreads();
    if (tid < 16) A[tid * 840 + XOFF + 3] = 0x3F80u;  // bias "one" column

    bf16x8 breg[KT];  // register-resident weight slice: KT frags = 4*KT VGPRs
    {
        const unsigned short* bp = Bp + (size_t)(s * CS + w * 16 + (lane & 15)) * KPAD + ((lane >> 4) << 3);
        #pragma unroll
        for (int kt = 0; kt < KT; ++kt)
            breg[kt] = *(const bf16x8*)(bp + kt * 32);
    }

    // epilogue ownership: thread -> (batch er, unit eu) ; 320 = 16*20 exactly
    const int er = tid / US;
    const int eu = tid - er * US;
    const int ug = s * US + eu;
    const float ppi = peepi[ug], ppf = peepf[ug], ppo = peepo[ug];
    float cst = 0.f;

    const int aoff = (lane & 15) * 840 + ((lane >> 4) << 3);

    for (int t = 0; t < TSTEPS; ++t) {
        // stage peer-independent parts first (hprev(t), x(t))
        if constexpr (HASP) {
            const unsigned short* hp = hprev + (size_t)t * 25600 + g * (GB * 400);
            for (int c = tid; c < 800; c += 320) {
                int r = c / 50, j = c - r * 50;
                *(bf16x8*)(&A[r * 840 + 400 + j * 8]) = *(const bf16x8*)(hp + r * 400 + j * 8);
            }
        }
        if (tid < 48) {
            int r = tid / 3, d = tid - (tid / 3) * 3;
            A[r * 840 + XOFF + d] = f2bf(x[((g * GB + r) * TSTEPS + t) * 3 + d]);
        }
        // wait for all 20 slices' h(t), then stage it
        if (t > 0) {
            if (tid == 0) {
                while (__hip_atomic_load(flag + t, __ATOMIC_ACQUIRE, __HIP_MEMORY_SCOPE_AGENT) < NSLICE) {}
            }
            __syncthreads();
            const unsigned short* src = hb + (t & 1) * (GB * 400);
            for (int c = tid; c < 800; c += 320) {
                int r = c / 50, j = c - r * 50;
                *(bf16x8*)(&A[r * 840 + j * 8]) = *(const bf16x8*)(src + r * 400 + j * 8);
            }
        }
        __syncthreads();

        // z[16 batches, 16 cols] for this wave's N-tile, K swept over KT frags
        floatx4 acc = {0.f, 0.f, 0.f, 0.f};
        #pragma unroll
        for (int kt = 0; kt < KT; ++kt) {
            bf16x8 a = *(const bf16x8*)(&A[aoff + kt * 32]);
            acc = __builtin_amdgcn_mfma_f32_16x16x32_bf16(a, breg[kt], acc, 0, 0, 0);
        }
        {
            const int zc = w * 16 + (lane & 15);
            const int zr = (lane >> 4) << 2;
            #pragma unroll
            for (int ri = 0; ri < 4; ++ri)
                Z[(zr + ri) * 84 + zc] = acc[ri];   // C/D layout: col=lane&15, row=(lane>>4)*4+ri
        }
        __syncthreads();

        // gates: z4 = (i,f,c,o) for (er, eu); peephole LSTM update, c fp32 in reg
        {
            const float4 z4 = *(const float4*)(&Z[er * 84 + (eu << 2)]);
            float iv = sigm_(z4.x + ppi * cst);
            float fv = sigm_(z4.y + ppf * cst);
            float cn = fv * cst + iv * tanh_(z4.z);
            float ov = sigm_(z4.w + ppo * cn);
            float hn = ov * tanh_(cn);
            cst = cn;
            unsigned short h16 = f2bf(hn);
            hb[((t + 1) & 1) * (GB * 400) + er * 400 + ug] = h16;
            hall[(size_t)t * 25600 + (g * GB + er) * 400 + ug] = h16;
        }
        __syncthreads();  // drains vmcnt before barrier -> stores complete
        if (tid == 0 && t + 1 < TSTEPS)
            __hip_atomic_fetch_add(flag + t + 1, 1, __ATOMIC_RELEASE, __HIP_MEMORY_SCOPE_AGENT);
    }
}

// MDN head: per block 32 rows (one b, 32 consecutive t). y = h2 @ Wmdn + b via MFMA
// (K=416 incl. ones row), then softmax(pi) / copy(mu) / exp(s) / tanh(rho) / sigm(eos).
__global__ __launch_bounds__(256)
void mdn_kernel(const unsigned short* __restrict__ h2,
                const unsigned short* __restrict__ Bm,
                float* __restrict__ out) {
    const int blk = blockIdx.x;
    const int b = blk / 25;
    const int t0 = (blk - b * 25) * 32;
    const int tid = threadIdx.x;
    const int lane = tid & 63;
    const int w = tid >> 6;
    const int m = w & 1, nh = w >> 1;   // wave = (M-tile, N-half)

    __shared__ unsigned short A[32 * 424];
    __shared__ float Z[32 * 132];
    __shared__ float rmax[32], rinv[32];

    for (int i = tid; i < 32 * 424; i += 256) A[i] = 0;
    __syncthreads();
    for (int c = tid; c < 32 * 50; c += 256) {
        int r = c / 50, j = c - r * 50;
        *(bf16x8*)(&A[r * 424 + j * 8]) = *(const bf16x8*)(h2 + (size_t)(t0 + r) * 25600 + b * 400 + j * 8);
    }
    if (tid < 32) A[tid * 424 + 400] = 0x3F80u;
    __syncthreads();

    floatx4 acc[4] = {{0,0,0,0},{0,0,0,0},{0,0,0,0},{0,0,0,0}};
    const int aoff = (m * 16 + (lane & 15)) * 424 + ((lane >> 4) << 3);
    #pragma unroll
    for (int kt = 0; kt < 13; ++kt) {
        bf16x8 a = *(const bf16x8*)(&A[aoff + kt * 32]);
        #pragma unroll
        for (int n = 0; n < 4; ++n) {
            const unsigned short* bp = Bm + (size_t)((nh * 4 + n) * 16 + (lane & 15)) * MK
                                          + ((lane >> 4) << 3) + kt * 32;
            acc[n] = __builtin_amdgcn_mfma_f32_16x16x32_bf16(a, *(const bf16x8*)bp, acc[n], 0, 0, 0);
        }
    }
    #pragma unroll
    for (int n = 0; n < 4; ++n) {
        int zc = (nh * 4 + n) * 16 + (lane & 15);
        int zr = m * 16 + ((lane >> 4) << 2);
        #pragma unroll
        for (int ri = 0; ri < 4; ++ri)
            Z[(zr + ri) * 132 + zc] = acc[n][ri];
    }
    __syncthreads();
    if (tid < 32) {
        float mx = -1e30f;
        for (int j = 0; j < 20; ++j) mx = fmaxf(mx, Z[tid * 132 + j]);
        float sm = 0.f;
        for (int j = 0; j < 20; ++j) sm += __expf(Z[tid * 132 + j] - mx);
        rmax[tid] = mx;
        rinv[tid] = 1.f / sm;
    }
    __syncthreads();
    for (int idx = tid; idx < 32 * 121; idx += 256) {
        int r = idx / 121, jo = idx - r * 121;
        float v = Z[r * 132 + jo];
        float o;
        if (jo < 20) o = __expf(v - rmax[r]) * rinv[r];
        else if (jo < 60) o = v;
        else if (jo < 100) o = __expf(v);
        else if (jo < 120) o = tanh_(v);
        else o = sigm_(v);
        out[(size_t)(b * TSTEPS + t0 + r) * 121 + jo] = o;
    }
}

extern "C" void kernel_launch(void* const* d_in, const int* in_sizes, int n_in,
                              void* d_out, int out_size, void* d_ws, size_t ws_size,
                              hipStream_t stream) {
    const float* x = (const float*)d_in[0];
    const float* Wx[3] = {(const float*)d_in[1], (const float*)d_in[7], (const float*)d_in[13]};
    const float* Wh[3] = {(const float*)d_in[2], (const float*)d_in[8], (const float*)d_in[14]};
    const float* bb[3] = {(const float*)d_in[3], (const float*)d_in[9], (const float*)d_in[15]};
    const float* pi[3] = {(const float*)d_in[4], (const float*)d_in[10], (const float*)d_in[16]};
    const float* pf[3] = {(const float*)d_in[5], (const float*)d_in[11], (const float*)d_in[17]};
    const float* po[3] = {(const float*)d_in[6], (const float*)d_in[12], (const float*)d_in[18]};
    const float* Wm = (const float*)d_in[19];
    const float* bm = (const float*)d_in[20];
    float* out = (float*)d_out;

    char* p = (char*)d_ws;
    size_t off = 0;
    auto alloc = [&](size_t bytes) -> void* {
        void* r = p + off;
        off = (off + bytes + 255) & ~(size_t)255;
        return r;
    };
    int* flags            = (int*)alloc((size_t)3 * NGROUP * TSTEPS * sizeof(int));
    unsigned short* hbuf  = (unsigned short*)alloc((size_t)3 * NGROUP * 2 * GB * 400 * 2);
    unsigned short* Bp    = (unsigned short*)alloc((size_t)3 * 1600 * KPAD * 2);
    unsigned short* Bm    = (unsigned short*)alloc((size_t)128 * MK * 2);
    unsigned short* hallA = (unsigned short*)alloc((size_t)TSTEPS * 64 * 400 * 2);
    unsigned short* hallB = (unsigned short*)alloc((size_t)TSTEPS * 64 * 400 * 2);
    // total ws use: ~90.3 MB

    hipMemsetAsync(flags, 0, (size_t)3 * NGROUP * TSTEPS * sizeof(int), stream);

    for (int l = 0; l < 3; ++l)
        pack_scan<<<5200, 256, 0, stream>>>(Wx[l], Wh[l], bb[l],
                                            Bp + (size_t)l * 1600 * KPAD, l > 0);
    pack_mdn<<<208, 256, 0, stream>>>(Wm, bm, Bm);

    scan_layer<13, 0><<<NGROUP * NSLICE, 320, 0, stream>>>(
        Bp, x, nullptr, hallA,
        hbuf, flags, pi[0], pf[0], po[0]);
    scan_layer<26, 1><<<NGROUP * NSLICE, 320, 0, stream>>>(
        Bp + (size_t)1600 * KPAD, x, hallA, hallB,
        hbuf + (size_t)NGROUP * 2 * GB * 400, flags + NGROUP * TSTEPS, pi[1], pf[1], po[1]);
    scan_layer<26, 1><<<NGROUP * NSLICE, 320, 0, stream>>>(
        Bp + (size_t)2 * 1600 * KPAD, x, hallB, hallA,
        hbuf + (size_t)2 * NGROUP * 2 * GB * 400, flags + 2 * NGROUP * TSTEPS, pi[2], pf[2], po[2]);

    mdn_kernel<<<1600, 256, 0, stream>>>(hallA, Bm, out);
}

// Round 2
// 5441.756 us; speedup vs baseline: 2.1993x; 2.1993x over previous
//
#include <hip/hip_runtime.h>

// DeepHandwritingPredictionModel: 3-layer peephole LSTM (B=64,T=800,U=400) + MDN(M=20)
// Round 2: single fused pipeline kernel.
//  - 120 recurrence blocks (3 layers x 4 batch-groups x 10 unit-slices), K=416 (own-h + x/bias)
//  - 80 preGEMM blocks (layers 1,2): compute zin(t) = [h_{l-1}(t), x(t), 1] @ Wx+b per step
//  - all cross-block exchange is tagged u32 words (tag<<16 | bf16) with RELAXED agent-scope
//    atomics: no fences, no flag aggregation. Depth-16 rings + progress backpressure.

#define TSTEPS 800
#define NG 4            // batch groups
#define GB 16           // batches per group
#define NSL 10          // unit-slices per (layer,group)
#define UB 40           // units per slice
#define CB 160          // cols per slice (4 gates * UB)
#define KP 416          // padded K (400 h | 3 x | 1 one | pad)
#define RD 16           // h-ring depth
#define ZS 168          // Z LDS stride (floats)

typedef __attribute__((ext_vector_type(8))) __bf16 bf16x8;
typedef __attribute__((ext_vector_type(4))) float floatx4;

struct Peeps { const float* pi[3]; const float* pf[3]; const float* po[3]; };

__device__ __forceinline__ unsigned short f2bf(float f) {
    unsigned int u = __float_as_uint(f);
    return (unsigned short)((u + 0x7FFFu + ((u >> 16) & 1u)) >> 16);
}
__device__ __forceinline__ float bf2f(unsigned u) { return __uint_as_float((u & 0xFFFFu) << 16); }
__device__ __forceinline__ float sigm_(float v) { return 1.f / (1.f + __expf(-v)); }
__device__ __forceinline__ float tanh_(float v) { float e = __expf(2.f * v); return 1.f - 2.f / (e + 1.f); }
__device__ __forceinline__ unsigned ld_a(const unsigned* p) {
    return __hip_atomic_load(p, __ATOMIC_RELAXED, __HIP_MEMORY_SCOPE_AGENT);
}
__device__ __forceinline__ void st_a(unsigned* p, unsigned v) {
    __hip_atomic_store(p, v, __ATOMIC_RELAXED, __HIP_MEMORY_SCOPE_AGENT);
}

// ---- weight packing ------------------------------------------------------
// col c in [0,1600): unit u=c>>2, gate=c&3 (i,f,c,o), orig col co=gate*400+u.
// Recurrence pack: k<400: Wh[k]; (l==0 only) k in 400..402: Wx rows, k==403: bias.
__global__ void pack_rec(const float* __restrict__ Wx, const float* __restrict__ Wh,
                         const float* __restrict__ bias, unsigned short* __restrict__ dst,
                         int is_l0) {
    int idx = blockIdx.x * 256 + threadIdx.x;
    if (idx >= 1600 * KP) return;
    int col = idx / KP, k = idx - col * KP;
    int co = (col & 3) * 400 + (col >> 2);
    float v = 0.f;
    if (k < 400) v = Wh[k * 1600 + co];
    else if (is_l0) {
        if (k < 403) v = Wx[(k - 400) * 1600 + co];
        else if (k == 403) v = bias[co];
    }
    dst[idx] = f2bf(v);
}
// preGEMM pack (layers 1,2; Wx is [403][1600], rows 0..2 = x, 3..402 = hprev):
// k<400: Wx[3+k]; k in 400..402: Wx[k-400]; k==403: bias.
__global__ void pack_pre(const float* __restrict__ Wx, const float* __restrict__ bias,
                         unsigned short* __restrict__ dst) {
    int idx = blockIdx.x * 256 + threadIdx.x;
    if (idx >= 1600 * KP) return;
    int col = idx / KP, k = idx - col * KP;
    int co = (col & 3) * 400 + (col >> 2);
    float v = 0.f;
    if (k < 400) v = Wx[(3 + k) * 1600 + co];
    else if (k < 403) v = Wx[(k - 400) * 1600 + co];
    else if (k == 403) v = bias[co];
    dst[idx] = f2bf(v);
}
__global__ void pack_x(const float* __restrict__ x, unsigned short* __restrict__ xp) {
    int idx = blockIdx.x * 256 + threadIdx.x;   // idx = t*64 + b
    if (idx >= TSTEPS * 64) return;
    int t = idx / 64, b = idx - t * 64;
    unsigned short o[4];
    for (int d = 0; d < 3; ++d) o[d] = f2bf(x[(b * TSTEPS + t) * 3 + d]);
    o[3] = 0x3F80u;
    *(uint2*)(xp + (size_t)idx * 4) = *(uint2*)o;
}
__global__ void pack_mdn(const float* __restrict__ Wm, const float* __restrict__ bm,
                         unsigned short* __restrict__ dst) {
    int idx = blockIdx.x * 256 + threadIdx.x;
    if (idx >= 128 * KP) return;
    int col = idx / KP, k = idx - col * KP;
    float v = 0.f;
    if (col < 121) {
        if (k < 400) v = Wm[k * 121 + col];
        else if (k == 400) v = bm[col];
    }
    dst[idx] = f2bf(v);
}

// ---- fused pipeline ------------------------------------------------------
// grid: [0,120) rec blocks (l=bid/40, g=(bid%40)/10, s=bid%10)
//       [120,200) pre blocks (lp=1+p/40, ...), 640 threads (10 waves).
// ring: [3][4][RD][16][400] u32 : h(t) stored at slot (t+1)&15, tag t+1
// zin : [2][4][RD][16][1600] u32: zin(t) stored at slot t&15, tag t+1
// prog: [0..80) pre-progress, [80..160) rec-progress (both step+1 watermarks)
__global__ __launch_bounds__(640)
void fused_scan(const unsigned short* __restrict__ Bp,
                const unsigned short* __restrict__ Bpre,
                const unsigned short* __restrict__ xpack,
                unsigned* __restrict__ ring,
                unsigned* __restrict__ zin,
                unsigned* __restrict__ prog,
                unsigned short* __restrict__ h2,
                Peeps pp) {
    const int tid = threadIdx.x;
    const int lane = tid & 63;
    const int w = tid >> 6;
    const int bid = blockIdx.x;

    __shared__ unsigned short A[16 * 424];
    __shared__ float Z[16 * ZS];

    for (int i = tid; i < 16 * 424; i += 640) A[i] = 0;

    const int er = tid / UB;            // batch row 0..15
    const int eu = tid - er * UB;       // unit-in-slice 0..39
    const int aoff = (lane & 15) * 424 + ((lane >> 4) << 3);
    const int zcl = w * 16 + (lane & 15);
    const int zr = (lane >> 4) << 2;

    if (bid < 120) {
        // ---------------- recurrence block ----------------
        const int l = bid / 40;
        const int g = (bid % 40) / 10;
        const int s = bid % 10;
        bf16x8 breg[13];
        {
            const unsigned short* bpp = Bp + (size_t)l * 1600 * KP
                + (size_t)(s * CB + w * 16 + (lane & 15)) * KP + ((lane >> 4) << 3);
            #pragma unroll
            for (int kt = 0; kt < 13; ++kt) breg[kt] = *(const bf16x8*)(bpp + kt * 32);
        }
        unsigned* ringL = ring + (size_t)(l * NG + g) * RD * 6400;
        const unsigned* zinL = zin + (size_t)((l - 1) * NG + g) * RD * 25600; // valid if l>0
        const unsigned* progPreL = prog + l * 40 + g * 10;                     // watched if l<2
        unsigned* progRecSlot = prog + 80 + (l - 1) * 40 + g * 10 + s;         // published if l>0

        const int ug = s * UB + eu;
        const float ppi = pp.pi[l][ug], ppf = pp.pf[l][ug], ppo = pp.po[l][ug];
        float cst = 0.f;
        __syncthreads();

        for (int t = 0; t < TSTEPS; ++t) {
            if (l == 0 && tid < 16) {
                const unsigned short* xp = xpack + ((size_t)t * 64 + g * 16 + tid) * 4;
                *(uint2*)(&A[tid * 424 + 400]) = *(const uint2*)xp;
            }
            if (l < 2 && tid == 0 && t >= 16) {   // h-ring overwrite backpressure (pre consumers)
                int need = t - 15;
                for (;;) {
                    unsigned mn = 0xFFFFFFFFu;
                    for (int q = 0; q < 10; ++q) mn = min(mn, ld_a(progPreL + q));
                    if ((int)mn >= need) break;
                    __builtin_amdgcn_s_sleep(1);
                }
            }
            if (t > 0) {   // poll + stage own-layer h(t-1): slot t&15, tag t
                const unsigned* src = ringL + (size_t)(t & 15) * 6400 + er * 400 + eu * 10;
                const unsigned want = (unsigned)t << 16;
                unsigned v[10];
                for (;;) {
                    bool ok = true;
                    #pragma unroll
                    for (int q = 0; q < 10; ++q) {
                        v[q] = ld_a(src + q);
                        ok &= ((v[q] & 0xFFFF0000u) == want);
                    }
                    if (ok) break;
                }
                #pragma unroll
                for (int q = 0; q < 10; ++q)
                    A[er * 424 + eu * 10 + q] = (unsigned short)(v[q] & 0xFFFFu);
            }
            __syncthreads();

            floatx4 a0 = {0, 0, 0, 0}, a1 = {0, 0, 0, 0};
            #pragma unroll
            for (int kt = 0; kt < 13; ++kt) {
                bf16x8 a = *(const bf16x8*)(&A[aoff + kt * 32]);
                if (kt & 1) a1 = __builtin_amdgcn_mfma_f32_16x16x32_bf16(a, breg[kt], a1, 0, 0, 0);
                else        a0 = __builtin_amdgcn_mfma_f32_16x16x32_bf16(a, breg[kt], a0, 0, 0, 0);
            }
            #pragma unroll
            for (int ri = 0; ri < 4; ++ri) Z[(zr + ri) * ZS + zcl] = a0[ri] + a1[ri];
            __syncthreads();

            {
                float4 z4 = *(const float4*)(&Z[er * ZS + (eu << 2)]);
                if (l > 0) {   // add zin(t): slot t&15, tag t+1
                    const unsigned* zp = zinL + (size_t)(t & 15) * 25600 + er * 1600 + (s * CB + (eu << 2));
                    const unsigned want2 = (unsigned)(t + 1) << 16;
                    unsigned u0, u1, u2, u3;
                    for (;;) {
                        u0 = ld_a(zp); u1 = ld_a(zp + 1); u2 = ld_a(zp + 2); u3 = ld_a(zp + 3);
                        if (((u0 & 0xFFFF0000u) == want2) & ((u1 & 0xFFFF0000u) == want2) &
                            ((u2 & 0xFFFF0000u) == want2) & ((u3 & 0xFFFF0000u) == want2)) break;
                    }
                    z4.x += bf2f(u0); z4.y += bf2f(u1); z4.z += bf2f(u2); z4.w += bf2f(u3);
                }
                float iv = sigm_(z4.x + ppi * cst);
                float fv = sigm_(z4.y + ppf * cst);
                float cn = fv * cst + iv * tanh_(z4.z);
                float ov = sigm_(z4.w + ppo * cn);
                float hn = ov * tanh_(cn);
                cst = cn;
                unsigned short h16 = f2bf(hn);
                st_a(ringL + (size_t)((t + 1) & 15) * 6400 + er * 400 + ug,
                     ((unsigned)(t + 1) << 16) | h16);
                if (l == 2) h2[(size_t)t * 25600 + (g * GB + er) * 400 + ug] = h16;
            }
            __syncthreads();
            if (l > 0 && tid == 0) st_a(progRecSlot, (unsigned)(t + 1));
        }
    } else {
        // ---------------- preGEMM block ----------------
        const int p = bid - 120;
        const int lp = 1 + p / 40;          // consumer layer (1 or 2)
        const int g = (p % 40) / 10;
        const int s = p % 10;
        bf16x8 breg[13];
        {
            const unsigned short* bpp = Bpre + (size_t)(lp - 1) * 1600 * KP
                + (size_t)(s * CB + w * 16 + (lane & 15)) * KP + ((lane >> 4) << 3);
            #pragma unroll
            for (int kt = 0; kt < 13; ++kt) breg[kt] = *(const bf16x8*)(bpp + kt * 32);
        }
        const unsigned* ringS = ring + (size_t)((lp - 1) * NG + g) * RD * 6400;
        unsigned* zinL = zin + (size_t)((lp - 1) * NG + g) * RD * 25600;
        unsigned* progSlot = prog + (lp - 1) * 40 + g * 10 + s;
        const unsigned* progRecL = prog + 80 + (lp - 1) * 40 + g * 10;
        const int cg = s * CB + w * 16 + (lane & 15);
        __syncthreads();

        for (int t = 0; t < TSTEPS; ++t) {
            if (tid < 16) {
                const unsigned short* xp = xpack + ((size_t)t * 64 + g * 16 + tid) * 4;
                *(uint2*)(&A[tid * 424 + 400]) = *(const uint2*)xp;
            }
            {   // poll + stage h_{lp-1}(t): slot (t+1)&15, tag t+1
                const unsigned* src = ringS + (size_t)((t + 1) & 15) * 6400 + er * 400 + eu * 10;
                const unsigned want = (unsigned)(t + 1) << 16;
                unsigned v[10];
                for (;;) {
                    bool ok = true;
                    #pragma unroll
                    for (int q = 0; q < 10; ++q) {
                        v[q] = ld_a(src + q);
                        ok &= ((v[q] & 0xFFFF0000u) == want);
                    }
                    if (ok) break;
                }
                #pragma unroll
                for (int q = 0; q < 10; ++q)
                    A[er * 424 + eu * 10 + q] = (unsigned short)(v[q] & 0xFFFFu);
            }
            if (tid == 0 && t >= 16) {   // zin-ring overwrite backpressure
                int need = t - 15;
                for (;;) {
                    unsigned mn = 0xFFFFFFFFu;
                    for (int q = 0; q < 10; ++q) mn = min(mn, ld_a(progRecL + q));
                    if ((int)mn >= need) break;
                    __builtin_amdgcn_s_sleep(1);
                }
            }
            __syncthreads();
            if (tid == 0) st_a(progSlot, (unsigned)(t + 1));   // consumed h(t)

            floatx4 a0 = {0, 0, 0, 0}, a1 = {0, 0, 0, 0};
            #pragma unroll
            for (int kt = 0; kt < 13; ++kt) {
                bf16x8 a = *(const bf16x8*)(&A[aoff + kt * 32]);
                if (kt & 1) a1 = __builtin_amdgcn_mfma_f32_16x16x32_bf16(a, breg[kt], a1, 0, 0, 0);
                else        a0 = __builtin_amdgcn_mfma_f32_16x16x32_bf16(a, breg[kt], a0, 0, 0, 0);
            }
            {
                const unsigned tagz = (unsigned)(t + 1) << 16;
                unsigned* zb = zinL + (size_t)(t & 15) * 25600;
                #pragma unroll
                for (int ri = 0; ri < 4; ++ri)
                    st_a(zb + (size_t)(zr + ri) * 1600 + cg, tagz | f2bf(a0[ri] + a1[ri]));
            }
            __syncthreads();
        }
    }
}

// ---- MDN head ------------------------------------------------------------
__global__ __launch_bounds__(256)
void mdn_kernel(const unsigned short* __restrict__ h2,
                const unsigned short* __restrict__ Bm,
                float* __restrict__ out) {
    const int blk = blockIdx.x;
    const int b = blk / 25;
    const int t0 = (blk - b * 25) * 32;
    const int tid = threadIdx.x;
    const int lane = tid & 63;
    const int w = tid >> 6;
    const int m = w & 1, nh = w >> 1;

    __shared__ unsigned short A[32 * 424];
    __shared__ float Z[32 * 132];
    __shared__ float rmax[32], rinv[32];

    for (int i = tid; i < 32 * 424; i += 256) A[i] = 0;
    __syncthreads();
    for (int c = tid; c < 32 * 50; c += 256) {
        int r = c / 50, j = c - r * 50;
        *(bf16x8*)(&A[r * 424 + j * 8]) = *(const bf16x8*)(h2 + (size_t)(t0 + r) * 25600 + b * 400 + j * 8);
    }
    if (tid < 32) A[tid * 424 + 400] = 0x3F80u;
    __syncthreads();

    floatx4 acc[4] = {{0,0,0,0},{0,0,0,0},{0,0,0,0},{0,0,0,0}};
    const int aoff = (m * 16 + (lane & 15)) * 424 + ((lane >> 4) << 3);
    #pragma unroll
    for (int kt = 0; kt < 13; ++kt) {
        bf16x8 a = *(const bf16x8*)(&A[aoff + kt * 32]);
        #pragma unroll
        for (int n = 0; n < 4; ++n) {
            const unsigned short* bp = Bm + (size_t)((nh * 4 + n) * 16 + (lane & 15)) * KP
                                          + ((lane >> 4) << 3) + kt * 32;
            acc[n] = __builtin_amdgcn_mfma_f32_16x16x32_bf16(a, *(const bf16x8*)bp, acc[n], 0, 0, 0);
        }
    }
    #pragma unroll
    for (int n = 0; n < 4; ++n) {
        int zc = (nh * 4 + n) * 16 + (lane & 15);
        int zrow = m * 16 + ((lane >> 4) << 2);
        #pragma unroll
        for (int ri = 0; ri < 4; ++ri)
            Z[(zrow + ri) * 132 + zc] = acc[n][ri];
    }
    __syncthreads();
    if (tid < 32) {
        float mx = -1e30f;
        for (int j = 0; j < 20; ++j) mx = fmaxf(mx, Z[tid * 132 + j]);
        float sm = 0.f;
        for (int j = 0; j < 20; ++j) sm += __expf(Z[tid * 132 + j] - mx);
        rmax[tid] = mx;
        rinv[tid] = 1.f / sm;
    }
    __syncthreads();
    for (int idx = tid; idx < 32 * 121; idx += 256) {
        int r = idx / 121, jo = idx - r * 121;
        float v = Z[r * 132 + jo];
        float o;
        if (jo < 20) o = __expf(v - rmax[r]) * rinv[r];
        else if (jo < 60) o = v;
        else if (jo < 100) o = __expf(v);
        else if (jo < 120) o = tanh_(v);
        else o = sigm_(v);
        out[(size_t)(b * TSTEPS + t0 + r) * 121 + jo] = o;
    }
}

extern "C" void kernel_launch(void* const* d_in, const int* in_sizes, int n_in,
                              void* d_out, int out_size, void* d_ws, size_t ws_size,
                              hipStream_t stream) {
    const float* x = (const float*)d_in[0];
    const float* Wx[3] = {(const float*)d_in[1], (const float*)d_in[7], (const float*)d_in[13]};
    const float* Wh[3] = {(const float*)d_in[2], (const float*)d_in[8], (const float*)d_in[14]};
    const float* bb[3] = {(const float*)d_in[3], (const float*)d_in[9], (const float*)d_in[15]};
    Peeps pp;
    for (int l = 0; l < 3; ++l) {
        pp.pi[l] = (const float*)d_in[4 + 6 * l];
        pp.pf[l] = (const float*)d_in[5 + 6 * l];
        pp.po[l] = (const float*)d_in[6 + 6 * l];
    }
    const float* Wm = (const float*)d_in[19];
    const float* bm = (const float*)d_in[20];
    float* out = (float*)d_out;

    char* base = (char*)d_ws;
    size_t off = 0;
    auto alloc = [&](size_t bytes) -> void* {
        void* r = base + off;
        off = (off + bytes + 255) & ~(size_t)255;
        return r;
    };
    unsigned* prog        = (unsigned*)alloc(160 * sizeof(unsigned));
    unsigned* ring        = (unsigned*)alloc((size_t)3 * NG * RD * 6400 * 4);      // 4.9 MB
    unsigned* zin         = (unsigned*)alloc((size_t)2 * NG * RD * 25600 * 4);     // 13.1 MB
    unsigned short* Bp    = (unsigned short*)alloc((size_t)3 * 1600 * KP * 2);     // 4.0 MB
    unsigned short* Bpre  = (unsigned short*)alloc((size_t)2 * 1600 * KP * 2);     // 2.7 MB
    unsigned short* Bm    = (unsigned short*)alloc((size_t)128 * KP * 2);
    unsigned short* xpk   = (unsigned short*)alloc((size_t)TSTEPS * 64 * 4 * 2);
    unsigned short* h2    = (unsigned short*)alloc((size_t)TSTEPS * 64 * 400 * 2); // 41 MB

    hipMemsetAsync(prog, 0, 160 * sizeof(unsigned), stream);

    for (int l = 0; l < 3; ++l)
        pack_rec<<<2600, 256, 0, stream>>>(Wx[l], Wh[l], bb[l], Bp + (size_t)l * 1600 * KP, l == 0);
    pack_pre<<<2600, 256, 0, stream>>>(Wx[1], bb[1], Bpre);
    pack_pre<<<2600, 256, 0, stream>>>(Wx[2], bb[2], Bpre + (size_t)1600 * KP);
    pack_x<<<200, 256, 0, stream>>>(x, xpk);
    pack_mdn<<<208, 256, 0, stream>>>(Wm, bm, Bm);

    fused_scan<<<200, 640, 0, stream>>>(Bp, Bpre, xpk, ring, zin, prog, h2, pp);

    mdn_kernel<<<1600, 256, 0, stream>>>(h2, Bm, out);
}

// Round 3
// 3770.951 us; speedup vs baseline: 3.1737x; 1.4431x over previous
//
#include <hip/hip_runtime.h>

// DeepHandwritingPredictionModel: 3-layer peephole LSTM (B=64,T=800,U=400) + MDN(M=20)
// Round 3: flag-based (seq-word) exchange, untagged packed bf16 data, ballot polling.
//  - 60 rec blocks (3 layers x 4 groups x 5 slices of 320 cols), 40 pre blocks.
//  - producer: data stores -> __syncthreads (vmcnt drain = release) -> 1 seq store.
//  - consumer: wave-0 ballot poll of 5-15 seq words, then one-shot wide data reads.
//  - backpressure amortized every 8 steps inside the same ballot poll (RD=16 slack).

#define TSTEPS 800
#define NG 4            // batch groups
#define GB 16           // batches per group
#define NSL 5           // unit-slices per (layer,group)
#define UB 80           // units per slice
#define CB 320          // cols per slice (4 gates * UB)
#define KP 416          // padded K (400 h | 3 x | 1 one | pad)
#define RD 16           // ring depth
#define AS 424          // A LDS stride (bf16)
#define ZS 332          // Z LDS stride (f32)  (332%4==0 for float4; breaks bank alias)
#define ZIS 336         // Zin LDS stride (bf16) (16B multiple)

typedef __attribute__((ext_vector_type(8))) __bf16 bf16x8;
typedef __attribute__((ext_vector_type(4))) float floatx4;

struct Peeps { const float* pi[3]; const float* pf[3]; const float* po[3]; };

__device__ __forceinline__ unsigned short f2bf(float f) {
    unsigned int u = __float_as_uint(f);
    return (unsigned short)((u + 0x7FFFu + ((u >> 16) & 1u)) >> 16);
}
__device__ __forceinline__ float bf_lo(unsigned u) { return __uint_as_float(u << 16); }
__device__ __forceinline__ float bf_hi(unsigned u) { return __uint_as_float(u & 0xFFFF0000u); }
__device__ __forceinline__ float sigm_(float v) { return 1.f / (1.f + __expf(-v)); }
__device__ __forceinline__ float tanh_(float v) { float e = __expf(2.f * v); return 1.f - 2.f / (e + 1.f); }
__device__ __forceinline__ unsigned ld_a(const unsigned* p) {
    return __hip_atomic_load(p, __ATOMIC_RELAXED, __HIP_MEMORY_SCOPE_AGENT);
}
__device__ __forceinline__ void st_a(unsigned* p, unsigned v) {
    __hip_atomic_store(p, v, __ATOMIC_RELAXED, __HIP_MEMORY_SCOPE_AGENT);
}

// ---- weight packing (unchanged layouts) ----------------------------------
__global__ void pack_rec(const float* __restrict__ Wx, const float* __restrict__ Wh,
                         const float* __restrict__ bias, unsigned short* __restrict__ dst,
                         int is_l0) {
    int idx = blockIdx.x * 256 + threadIdx.x;
    if (idx >= 1600 * KP) return;
    int col = idx / KP, k = idx - col * KP;
    int co = (col & 3) * 400 + (col >> 2);
    float v = 0.f;
    if (k < 400) v = Wh[k * 1600 + co];
    else if (is_l0) {
        if (k < 403) v = Wx[(k - 400) * 1600 + co];
        else if (k == 403) v = bias[co];
    }
    dst[idx] = f2bf(v);
}
__global__ void pack_pre(const float* __restrict__ Wx, const float* __restrict__ bias,
                         unsigned short* __restrict__ dst) {
    int idx = blockIdx.x * 256 + threadIdx.x;
    if (idx >= 1600 * KP) return;
    int col = idx / KP, k = idx - col * KP;
    int co = (col & 3) * 400 + (col >> 2);
    float v = 0.f;
    if (k < 400) v = Wx[(3 + k) * 1600 + co];
    else if (k < 403) v = Wx[(k - 400) * 1600 + co];
    else if (k == 403) v = bias[co];
    dst[idx] = f2bf(v);
}
__global__ void pack_x(const float* __restrict__ x, unsigned short* __restrict__ xp) {
    int idx = blockIdx.x * 256 + threadIdx.x;   // idx = t*64 + b
    if (idx >= TSTEPS * 64) return;
    int t = idx / 64, b = idx - t * 64;
    unsigned short o[4];
    for (int d = 0; d < 3; ++d) o[d] = f2bf(x[(b * TSTEPS + t) * 3 + d]);
    o[3] = 0x3F80u;
    *(uint2*)(xp + (size_t)idx * 4) = *(uint2*)o;
}
__global__ void pack_mdn(const float* __restrict__ Wm, const float* __restrict__ bm,
                         unsigned short* __restrict__ dst) {
    int idx = blockIdx.x * 256 + threadIdx.x;
    if (idx >= 128 * KP) return;
    int col = idx / KP, k = idx - col * KP;
    float v = 0.f;
    if (col < 121) {
        if (k < 400) v = Wm[k * 121 + col];
        else if (k == 400) v = bm[col];
    }
    dst[idx] = f2bf(v);
}

// ---- fused pipeline ------------------------------------------------------
// grid 100 x 640: bid<60 rec (l=bid/20,g=(bid%20)/5,s=bid%5); else pre (lp=1+p/20,...)
// ring: [3][NG][RD][16][200] u32 (packed 2xbf16)   h(t) at slot t&15
// zin : [2][NG][RD][16][800] u32 (packed 2xbf16)   zin(t) at slot t&15
// seqb: hseq[(l*NG+g)*16 + s] ; preseq at +192: [((lp-1)*NG+g)*16 + s]
//   rec seq = t+1  <=> h(0..t) stored AND zin(0..t) consumed
//   pre seq = t+1  <=> zin(0..t) stored AND h(0..t) consumed
__global__ __launch_bounds__(640)
void fused_scan(const unsigned short* __restrict__ Bp,
                const unsigned short* __restrict__ Bpre,
                const unsigned short* __restrict__ xpack,
                unsigned* __restrict__ ring,
                unsigned* __restrict__ zin,
                unsigned* __restrict__ seqb,
                unsigned short* __restrict__ h2,
                Peeps pp) {
    const int tid = threadIdx.x;
    const int lane = tid & 63;
    const int w = tid >> 6;
    const int bid = blockIdx.x;

    __shared__ unsigned short A[16 * AS];
    __shared__ float Z[16 * ZS];
    __shared__ unsigned short Zin[16 * ZIS];

    for (int i = tid; i < 16 * AS; i += 640) A[i] = 0;

    const int aoff = (lane & 15) * AS + ((lane >> 4) << 3);
    const int zc0 = w * 32 + (lane & 15);
    const int zr = (lane >> 4) << 2;
    const int er = tid / 40;          // batch row 0..15
    const int up = tid - er * 40;     // unit-pair 0..39

    if (bid < 60) {
        // ---------------- recurrence block ----------------
        const int l = bid / 20;
        const int g = (bid % 20) / 5;
        const int s = bid % 5;
        bf16x8 breg[2][13];
        #pragma unroll
        for (int n = 0; n < 2; ++n) {
            const unsigned short* bpp = Bp + (size_t)l * 1600 * KP
                + (size_t)(s * CB + w * 32 + n * 16 + (lane & 15)) * KP + ((lane >> 4) << 3);
            #pragma unroll
            for (int kt = 0; kt < 13; ++kt) breg[n][kt] = *(const bf16x8*)(bpp + kt * 32);
        }
        unsigned* hs_own  = seqb + (l * NG + g) * 16;
        const unsigned* ps_up = seqb + 192 + ((l - 1) * NG + g) * 16;   // l>0
        const unsigned* ps_dn = seqb + 192 + (l * NG + g) * 16;         // l<2
        unsigned* ringL = ring + (size_t)(l * NG + g) * RD * 3200;
        const unsigned* zinL = zin + (size_t)((l - 1) * NG + g) * RD * 12800;

        const int ug0 = s * UB + 2 * up;
        const float pi0 = pp.pi[l][ug0], pi1 = pp.pi[l][ug0 + 1];
        const float pf0 = pp.pf[l][ug0], pf1 = pp.pf[l][ug0 + 1];
        const float po0 = pp.po[l][ug0], po1 = pp.po[l][ug0 + 1];
        float c0 = 0.f, c1 = 0.f;
        __syncthreads();

        for (int t = 0; t < TSTEPS; ++t) {
            if (w == 0) {   // ballot poll: deps + amortized backpressure
                const unsigned* fp = nullptr; unsigned need = 0;
                if (lane < 5)       { if (t > 0) { fp = hs_own + lane; need = (unsigned)t; } }
                else if (lane < 10) { if (l > 0) { fp = ps_up + (lane - 5); need = (unsigned)(t + 1); } }
                else if (lane < 15) { if (l < 2 && t >= 16 && (t & 7) == 0) { fp = ps_dn + (lane - 10); need = (unsigned)(t - 8); } }
                bool ok = (fp == nullptr) || (ld_a(fp) >= need);
                while (!__all(ok)) { if (!ok) ok = ld_a(fp) >= need; }
            }
            __syncthreads();

            if (t > 0) {   // one-shot read of h(t-1), slot (t-1)&15
                const unsigned* src = ringL + (size_t)((t - 1) & 15) * 3200;
                for (int i = tid; i < 800; i += 640) {
                    int r = i / 50, c4 = (i - r * 50) * 4;
                    unsigned v0 = ld_a(src + r * 200 + c4);
                    unsigned v1 = ld_a(src + r * 200 + c4 + 1);
                    unsigned v2 = ld_a(src + r * 200 + c4 + 2);
                    unsigned v3 = ld_a(src + r * 200 + c4 + 3);
                    unsigned* dst = (unsigned*)&A[r * AS + c4 * 2];
                    dst[0] = v0; dst[1] = v1; dst[2] = v2; dst[3] = v3;
                }
            }
            if (l == 0 && tid < 16)
                *(uint2*)(&A[tid * AS + 400]) = *(const uint2*)(xpack + ((size_t)t * 64 + g * 16 + tid) * 4);
            if (l > 0) {   // one-shot read of zin(t) slice, slot t&15
                const unsigned* zp = zinL + (size_t)(t & 15) * 12800 + er * 800 + s * 160 + up * 4;
                unsigned z0 = ld_a(zp), z1 = ld_a(zp + 1), z2 = ld_a(zp + 2), z3 = ld_a(zp + 3);
                unsigned* zd = (unsigned*)&Zin[er * ZIS + up * 8];
                zd[0] = z0; zd[1] = z1; zd[2] = z2; zd[3] = z3;
            }
            __syncthreads();

            floatx4 a0 = {0, 0, 0, 0}, a1 = {0, 0, 0, 0};
            #pragma unroll
            for (int kt = 0; kt < 13; ++kt) {
                bf16x8 a = *(const bf16x8*)(&A[aoff + kt * 32]);
                a0 = __builtin_amdgcn_mfma_f32_16x16x32_bf16(a, breg[0][kt], a0, 0, 0, 0);
                a1 = __builtin_amdgcn_mfma_f32_16x16x32_bf16(a, breg[1][kt], a1, 0, 0, 0);
            }
            #pragma unroll
            for (int ri = 0; ri < 4; ++ri) {
                Z[(zr + ri) * ZS + zc0] = a0[ri];
                Z[(zr + ri) * ZS + zc0 + 16] = a1[ri];
            }
            __syncthreads();

            {   // epilogue: 2 units per thread
                float4 za = *(const float4*)(&Z[er * ZS + 8 * up]);
                float4 zb = *(const float4*)(&Z[er * ZS + 8 * up + 4]);
                if (l > 0) {
                    const unsigned* q = (const unsigned*)&Zin[er * ZIS + 8 * up];
                    unsigned q0 = q[0], q1 = q[1], q2 = q[2], q3 = q[3];
                    za.x += bf_lo(q0); za.y += bf_hi(q0); za.z += bf_lo(q1); za.w += bf_hi(q1);
                    zb.x += bf_lo(q2); zb.y += bf_hi(q2); zb.z += bf_lo(q3); zb.w += bf_hi(q3);
                }
                float iv = sigm_(za.x + pi0 * c0);
                float fv = sigm_(za.y + pf0 * c0);
                float cn = fv * c0 + iv * tanh_(za.z);
                float ov = sigm_(za.w + po0 * cn);
                float h0 = ov * tanh_(cn);
                c0 = cn;
                iv = sigm_(zb.x + pi1 * c1);
                fv = sigm_(zb.y + pf1 * c1);
                cn = fv * c1 + iv * tanh_(zb.z);
                ov = sigm_(zb.w + po1 * cn);
                float h1 = ov * tanh_(cn);
                c1 = cn;
                unsigned packh = (unsigned)f2bf(h0) | ((unsigned)f2bf(h1) << 16);
                st_a(ringL + (size_t)(t & 15) * 3200 + er * 200 + s * 40 + up, packh);
                if (l == 2)
                    *(unsigned*)&h2[(size_t)t * 25600 + (g * GB + er) * 400 + ug0] = packh;
            }
            __syncthreads();   // drains vmcnt -> data stores globally visible (release)
            if (tid == 0) st_a(hs_own + s, (unsigned)(t + 1));
        }
    } else {
        // ---------------- preGEMM block ----------------
        const int p = bid - 60;
        const int lp = 1 + p / 20;
        const int g = (p % 20) / 5;
        const int s = p % 5;
        bf16x8 breg[2][13];
        #pragma unroll
        for (int n = 0; n < 2; ++n) {
            const unsigned short* bpp = Bpre + (size_t)(lp - 1) * 1600 * KP
                + (size_t)(s * CB + w * 32 + n * 16 + (lane & 15)) * KP + ((lane >> 4) << 3);
            #pragma unroll
            for (int kt = 0; kt < 13; ++kt) breg[n][kt] = *(const bf16x8*)(bpp + kt * 32);
        }
        const unsigned* hs_up = seqb + ((lp - 1) * NG + g) * 16;
        const unsigned* hs_cons = seqb + (lp * NG + g) * 16;
        unsigned* pseq = seqb + 192 + ((lp - 1) * NG + g) * 16 + s;
        const unsigned* ringS = ring + (size_t)((lp - 1) * NG + g) * RD * 3200;
        unsigned* zinD = zin + (size_t)((lp - 1) * NG + g) * RD * 12800;
        __syncthreads();

        for (int t = 0; t < TSTEPS; ++t) {
            if (w == 0) {
                const unsigned* fp = nullptr; unsigned need = 0;
                if (lane < 5)       { fp = hs_up + lane; need = (unsigned)(t + 1); }
                else if (lane < 10) { if (t >= 16 && (t & 7) == 0) { fp = hs_cons + (lane - 5); need = (unsigned)(t - 8); } }
                bool ok = (fp == nullptr) || (ld_a(fp) >= need);
                while (!__all(ok)) { if (!ok) ok = ld_a(fp) >= need; }
            }
            __syncthreads();

            {   // one-shot read of h_{lp-1}(t), slot t&15
                const unsigned* src = ringS + (size_t)(t & 15) * 3200;
                for (int i = tid; i < 800; i += 640) {
                    int r = i / 50, c4 = (i - r * 50) * 4;
                    unsigned v0 = ld_a(src + r * 200 + c4);
                    unsigned v1 = ld_a(src + r * 200 + c4 + 1);
                    unsigned v2 = ld_a(src + r * 200 + c4 + 2);
                    unsigned v3 = ld_a(src + r * 200 + c4 + 3);
                    unsigned* dst = (unsigned*)&A[r * AS + c4 * 2];
                    dst[0] = v0; dst[1] = v1; dst[2] = v2; dst[3] = v3;
                }
            }
            if (tid < 16)
                *(uint2*)(&A[tid * AS + 400]) = *(const uint2*)(xpack + ((size_t)t * 64 + g * 16 + tid) * 4);
            __syncthreads();

            floatx4 a0 = {0, 0, 0, 0}, a1 = {0, 0, 0, 0};
            #pragma unroll
            for (int kt = 0; kt < 13; ++kt) {
                bf16x8 a = *(const bf16x8*)(&A[aoff + kt * 32]);
                a0 = __builtin_amdgcn_mfma_f32_16x16x32_bf16(a, breg[0][kt], a0, 0, 0, 0);
                a1 = __builtin_amdgcn_mfma_f32_16x16x32_bf16(a, breg[1][kt], a1, 0, 0, 0);
            }
            #pragma unroll
            for (int ri = 0; ri < 4; ++ri) {
                Z[(zr + ri) * ZS + zc0] = a0[ri];
                Z[(zr + ri) * ZS + zc0 + 16] = a1[ri];
            }
            __syncthreads();

            {   // pack 8 z-values -> 4 dwords, store to zin ring
                float4 za = *(const float4*)(&Z[er * ZS + 8 * up]);
                float4 zb = *(const float4*)(&Z[er * ZS + 8 * up + 4]);
                unsigned* zd = zinD + (size_t)(t & 15) * 12800 + er * 800 + s * 160 + up * 4;
                st_a(zd,     (unsigned)f2bf(za.x) | ((unsigned)f2bf(za.y) << 16));
                st_a(zd + 1, (unsigned)f2bf(za.z) | ((unsigned)f2bf(za.w) << 16));
                st_a(zd + 2, (unsigned)f2bf(zb.x) | ((unsigned)f2bf(zb.y) << 16));
                st_a(zd + 3, (unsigned)f2bf(zb.z) | ((unsigned)f2bf(zb.w) << 16));
            }
            __syncthreads();   // release: zin stores drained before seq publish
            if (tid == 0) st_a(pseq, (unsigned)(t + 1));
        }
    }
}

// ---- MDN head (unchanged) ------------------------------------------------
__global__ __launch_bounds__(256)
void mdn_kernel(const unsigned short* __restrict__ h2,
                const unsigned short* __restrict__ Bm,
                float* __restrict__ out) {
    const int blk = blockIdx.x;
    const int b = blk / 25;
    const int t0 = (blk - b * 25) * 32;
    const int tid = threadIdx.x;
    const int lane = tid & 63;
    const int w = tid >> 6;
    const int m = w & 1, nh = w >> 1;

    __shared__ unsigned short A[32 * 424];
    __shared__ float Z[32 * 132];
    __shared__ float rmax[32], rinv[32];

    for (int i = tid; i < 32 * 424; i += 256) A[i] = 0;
    __syncthreads();
    for (int c = tid; c < 32 * 50; c += 256) {
        int r = c / 50, j = c - r * 50;
        *(bf16x8*)(&A[r * 424 + j * 8]) = *(const bf16x8*)(h2 + (size_t)(t0 + r) * 25600 + b * 400 + j * 8);
    }
    if (tid < 32) A[tid * 424 + 400] = 0x3F80u;
    __syncthreads();

    floatx4 acc[4] = {{0,0,0,0},{0,0,0,0},{0,0,0,0},{0,0,0,0}};
    const int aoff = (m * 16 + (lane & 15)) * 424 + ((lane >> 4) << 3);
    #pragma unroll
    for (int kt = 0; kt < 13; ++kt) {
        bf16x8 a = *(const bf16x8*)(&A[aoff + kt * 32]);
        #pragma unroll
        for (int n = 0; n < 4; ++n) {
            const unsigned short* bp = Bm + (size_t)((nh * 4 + n) * 16 + (lane & 15)) * KP
                                          + ((lane >> 4) << 3) + kt * 32;
            acc[n] = __builtin_amdgcn_mfma_f32_16x16x32_bf16(a, *(const bf16x8*)bp, acc[n], 0, 0, 0);
        }
    }
    #pragma unroll
    for (int n = 0; n < 4; ++n) {
        int zc = (nh * 4 + n) * 16 + (lane & 15);
        int zrow = m * 16 + ((lane >> 4) << 2);
        #pragma unroll
        for (int ri = 0; ri < 4; ++ri)
            Z[(zrow + ri) * 132 + zc] = acc[n][ri];
    }
    __syncthreads();
    if (tid < 32) {
        float mx = -1e30f;
        for (int j = 0; j < 20; ++j) mx = fmaxf(mx, Z[tid * 132 + j]);
        float sm = 0.f;
        for (int j = 0; j < 20; ++j) sm += __expf(Z[tid * 132 + j] - mx);
        rmax[tid] = mx;
        rinv[tid] = 1.f / sm;
    }
    __syncthreads();
    for (int idx = tid; idx < 32 * 121; idx += 256) {
        int r = idx / 121, jo = idx - r * 121;
        float v = Z[r * 132 + jo];
        float o;
        if (jo < 20) o = __expf(v - rmax[r]) * rinv[r];
        else if (jo < 60) o = v;
        else if (jo < 100) o = __expf(v);
        else if (jo < 120) o = tanh_(v);
        else o = sigm_(v);
        out[(size_t)(b * TSTEPS + t0 + r) * 121 + jo] = o;
    }
}

extern "C" void kernel_launch(void* const* d_in, const int* in_sizes, int n_in,
                              void* d_out, int out_size, void* d_ws, size_t ws_size,
                              hipStream_t stream) {
    const float* x = (const float*)d_in[0];
    const float* Wx[3] = {(const float*)d_in[1], (const float*)d_in[7], (const float*)d_in[13]};
    const float* Wh[3] = {(const float*)d_in[2], (const float*)d_in[8], (const float*)d_in[14]};
    const float* bb[3] = {(const float*)d_in[3], (const float*)d_in[9], (const float*)d_in[15]};
    Peeps pp;
    for (int l = 0; l < 3; ++l) {
        pp.pi[l] = (const float*)d_in[4 + 6 * l];
        pp.pf[l] = (const float*)d_in[5 + 6 * l];
        pp.po[l] = (const float*)d_in[6 + 6 * l];
    }
    const float* Wm = (const float*)d_in[19];
    const float* bm = (const float*)d_in[20];
    float* out = (float*)d_out;

    char* base = (char*)d_ws;
    size_t off = 0;
    auto alloc = [&](size_t bytes) -> void* {
        void* r = base + off;
        off = (off + bytes + 255) & ~(size_t)255;
        return r;
    };
    unsigned* seqb        = (unsigned*)alloc(320 * sizeof(unsigned));
    unsigned* ring        = (unsigned*)alloc((size_t)3 * NG * RD * 3200 * 4);   // 2.46 MB
    unsigned* zin         = (unsigned*)alloc((size_t)2 * NG * RD * 12800 * 4);  // 6.55 MB
    unsigned short* Bp    = (unsigned short*)alloc((size_t)3 * 1600 * KP * 2);  // 4.0 MB
    unsigned short* Bpre  = (unsigned short*)alloc((size_t)2 * 1600 * KP * 2);  // 2.7 MB
    unsigned short* Bm    = (unsigned short*)alloc((size_t)128 * KP * 2);
    unsigned short* xpk   = (unsigned short*)alloc((size_t)TSTEPS * 64 * 4 * 2);
    unsigned short* h2    = (unsigned short*)alloc((size_t)TSTEPS * 64 * 400 * 2); // 41 MB

    hipMemsetAsync(seqb, 0, 320 * sizeof(unsigned), stream);

    for (int l = 0; l < 3; ++l)
        pack_rec<<<2600, 256, 0, stream>>>(Wx[l], Wh[l], bb[l], Bp + (size_t)l * 1600 * KP, l == 0);
    pack_pre<<<2600, 256, 0, stream>>>(Wx[1], bb[1], Bpre);
    pack_pre<<<2600, 256, 0, stream>>>(Wx[2], bb[2], Bpre + (size_t)1600 * KP);
    pack_x<<<200, 256, 0, stream>>>(x, xpk);
    pack_mdn<<<208, 256, 0, stream>>>(Wm, bm, Bm);

    fused_scan<<<100, 640, 0, stream>>>(Bp, Bpre, xpk, ring, zin, seqb, h2, pp);

    mdn_kernel<<<1600, 256, 0, stream>>>(h2, Bm, out);
}

// Round 4
// 3034.233 us; speedup vs baseline: 3.9443x; 1.2428x over previous
//
#include <hip/hip_runtime.h>

// DeepHandwritingPredictionModel: 3-layer peephole LSTM (B=64,T=800,U=400) + MDN(M=20)
// Round 4: tagged-data h exchange (1 LLC round trip in the recurrence cycle),
// stores drained under the next step's poll, zin/hring flag paths amortized.
//  - 60 rec blocks (3 layers x 4 groups x 5 slices of 320 cols), 640 thr (10 waves)
//  - 40 pre blocks (2 layers x 4 groups x 5 splits), TCH=2 steps/iter
//  - hx ring: depth 4, word = (t<<16)|bf16, cleared to 0xAA each launch.

#define TSTEPS 800
#define NG 4            // batch groups
#define GB 16           // batches per group
#define NSL 5           // slices / splits per (layer,group)
#define UB 80           // units per slice
#define CB 320          // cols per slice (4 gates * UB)
#define KP 416          // padded K (400 h | 3 x | 1 one | pad)
#define RD 16           // hring / zin ring depth
#define HXD 4           // tagged hx ring depth
#define AS 424          // A LDS stride (bf16)
#define ZS 332          // Z LDS stride (f32)

typedef __attribute__((ext_vector_type(8))) __bf16 bf16x8;
typedef __attribute__((ext_vector_type(4))) float floatx4;

struct Peeps { const float* pi[3]; const float* pf[3]; const float* po[3]; };

__device__ __forceinline__ unsigned short f2bf(float f) {
    unsigned int u = __float_as_uint(f);
    return (unsigned short)((u + 0x7FFFu + ((u >> 16) & 1u)) >> 16);
}
__device__ __forceinline__ float bf_lo(unsigned u) { return __uint_as_float(u << 16); }
__device__ __forceinline__ float bf_hi(unsigned u) { return __uint_as_float(u & 0xFFFF0000u); }
__device__ __forceinline__ float sigm_(float v) { return 1.f / (1.f + __expf(-v)); }
__device__ __forceinline__ float tanh_(float v) { float e = __expf(2.f * v); return 1.f - 2.f / (e + 1.f); }
__device__ __forceinline__ unsigned ld_a(const unsigned* p) {
    return __hip_atomic_load(p, __ATOMIC_RELAXED, __HIP_MEMORY_SCOPE_AGENT);
}
__device__ __forceinline__ void st_a(unsigned* p, unsigned v) {
    __hip_atomic_store(p, v, __ATOMIC_RELAXED, __HIP_MEMORY_SCOPE_AGENT);
}

// ---- weight packing ------------------------------------------------------
__global__ void pack_rec(const float* __restrict__ Wx, const float* __restrict__ Wh,
                         const float* __restrict__ bias, unsigned short* __restrict__ dst,
                         int is_l0) {
    int idx = blockIdx.x * 256 + threadIdx.x;
    if (idx >= 1600 * KP) return;
    int col = idx / KP, k = idx - col * KP;
    int co = (col & 3) * 400 + (col >> 2);
    float v = 0.f;
    if (k < 400) v = Wh[k * 1600 + co];
    else if (is_l0) {
        if (k < 403) v = Wx[(k - 400) * 1600 + co];
        else if (k == 403) v = bias[co];
    }
    dst[idx] = f2bf(v);
}
__global__ void pack_pre(const float* __restrict__ Wx, const float* __restrict__ bias,
                         unsigned short* __restrict__ dst) {
    int idx = blockIdx.x * 256 + threadIdx.x;
    if (idx >= 1600 * KP) return;
    int col = idx / KP, k = idx - col * KP;
    int co = (col & 3) * 400 + (col >> 2);
    float v = 0.f;
    if (k < 400) v = Wx[(3 + k) * 1600 + co];
    else if (k < 403) v = Wx[(k - 400) * 1600 + co];
    else if (k == 403) v = bias[co];
    dst[idx] = f2bf(v);
}
__global__ void pack_x(const float* __restrict__ x, unsigned short* __restrict__ xp) {
    int idx = blockIdx.x * 256 + threadIdx.x;   // idx = t*64 + b
    if (idx >= TSTEPS * 64) return;
    int t = idx / 64, b = idx - t * 64;
    unsigned short o[4];
    for (int d = 0; d < 3; ++d) o[d] = f2bf(x[(b * TSTEPS + t) * 3 + d]);
    o[3] = 0x3F80u;
    *(uint2*)(xp + (size_t)idx * 4) = *(uint2*)o;
}
__global__ void pack_mdn(const float* __restrict__ Wm, const float* __restrict__ bm,
                         unsigned short* __restrict__ dst) {
    int idx = blockIdx.x * 256 + threadIdx.x;
    if (idx >= 128 * KP) return;
    int col = idx / KP, k = idx - col * KP;
    float v = 0.f;
    if (col < 121) {
        if (k < 400) v = Wm[k * 121 + col];
        else if (k == 400) v = bm[col];
    }
    dst[idx] = f2bf(v);
}

// ---- fused pipeline ------------------------------------------------------
// grid 100 x 640: bid<60 rec (l=bid/20, g=(bid%20)/5, s=bid%5); else pre.
// hx   : [3][NG][HXD][16][400] u32 tagged (t<<16|bf16), slot t&3
// hring: [3][NG][RD][16][200] u32 packed 2xbf16, slot t&15 (for pre)
// zin  : [2][NG][RD][16][800] u32 packed 2xbf16, slot t&15
// seqb : FH[(l*NG+g)*NSL+s]*16 : rec progress (h(0..v-1) hring-visible)
//        FZ at +60*16: [(lz*NG+g)*NSL+sp]*16 : pre progress (zin(0..v-1) visible,
//        h(0..v-1) consumed)
__global__ __launch_bounds__(640)
void fused_scan(const unsigned short* __restrict__ Bp,
                const unsigned short* __restrict__ Bpre,
                const unsigned short* __restrict__ xpack,
                unsigned* __restrict__ hx,
                unsigned* __restrict__ hring,
                unsigned* __restrict__ zin,
                unsigned* __restrict__ seqb,
                unsigned* __restrict__ h2,      // [T][64][200] dwords (2xbf16)
                Peeps pp) {
    const int tid = threadIdx.x;
    const int lane = tid & 63;
    const int w = tid >> 6;
    const int bid = blockIdx.x;

    __shared__ unsigned short A[32 * AS];
    __shared__ float Z[16 * ZS];

    for (int i = tid; i < 32 * AS; i += 640) A[i] = 0;

    const int er = tid / 40;          // batch row 0..15
    const int up = tid - er * 40;     // unit-pair 0..39
    const int aoff = (lane & 15) * AS + ((lane >> 4) << 3);
    const int zc0 = w * 32 + (lane & 15);
    const int zr = (lane >> 4) << 2;

    if (bid < 60) {
        // ---------------- recurrence block ----------------
        const int l = bid / 20;
        const int g = (bid % 20) / 5;
        const int s = bid % 5;
        bf16x8 breg[2][13];
        #pragma unroll
        for (int n = 0; n < 2; ++n) {
            const unsigned short* bpp = Bp + (size_t)l * 1600 * KP
                + (size_t)(s * CB + w * 32 + n * 16 + (lane & 15)) * KP + ((lane >> 4) << 3);
            #pragma unroll
            for (int kt = 0; kt < 13; ++kt) breg[n][kt] = *(const bf16x8*)(bpp + kt * 32);
        }
        unsigned* hxL = hx + (size_t)(l * NG + g) * HXD * 6400;
        unsigned* ringL = hring + (size_t)(l * NG + g) * RD * 3200;
        const unsigned* zinL = zin + (size_t)((l - 1) * NG + g) * RD * 12800;
        unsigned* FHown = seqb + ((l * NG + g) * NSL + s) * 16;
        const unsigned* FZup = seqb + (60 + ((l - 1) * NG + g) * NSL) * 16;
        const unsigned* FZdn = seqb + (60 + (l * NG + g) * NSL) * 16;

        const int p0 = ((s + 1) % 5) * 80, p1 = ((s + 2) % 5) * 80;
        const int p2 = ((s + 3) % 5) * 80, p3 = ((s + 4) % 5) * 80;
        const int ug0 = s * UB + 2 * up;
        const float pi0 = pp.pi[l][ug0], pi1 = pp.pi[l][ug0 + 1];
        const float pf0 = pp.pf[l][ug0], pf1 = pp.pf[l][ug0 + 1];
        const float po0 = pp.po[l][ug0], po1 = pp.po[l][ug0 + 1];
        float c0 = 0.f, c1 = 0.f;

        __syncthreads();
        if (l == 0 && tid < 16)
            *(uint2*)(&A[tid * AS + 400]) = *(const uint2*)(xpack + ((size_t)0 * 64 + g * 16 + tid) * 4);
        __syncthreads();

        for (int t = 0; t < TSTEPS; ++t) {
            // ---- detect: poll peers' tagged h(t-1) + amortized flag gates ----
            {
                const unsigned want = (unsigned)(t - 1) << 16;
                const unsigned* hb = hxL + (size_t)((t + 3) & 3) * 6400 + er * 400 + 2 * up;
                const unsigned* fp = nullptr; unsigned fneed = 0;
                if (l > 0 && (t & 3) == 0 && tid < NSL) { fp = FZup + tid * 16; fneed = (unsigned)(t + 4); }
                else if (l < 2 && (t & 7) == 0 && tid >= NSL && tid < 2 * NSL) {
                    fp = FZdn + (tid - NSL) * 16; fneed = (unsigned)(t > 8 ? t - 8 : 0);
                }
                unsigned v0, v1, v2, v3, v4, v5, v6, v7;
                for (;;) {
                    bool ok = true;
                    if (t > 0) {
                        v0 = ld_a(hb + p0); v1 = ld_a(hb + p0 + 1);
                        v2 = ld_a(hb + p1); v3 = ld_a(hb + p1 + 1);
                        v4 = ld_a(hb + p2); v5 = ld_a(hb + p2 + 1);
                        v6 = ld_a(hb + p3); v7 = ld_a(hb + p3 + 1);
                        ok = ((v0 & 0xFFFF0000u) == want) & ((v1 & 0xFFFF0000u) == want) &
                             ((v2 & 0xFFFF0000u) == want) & ((v3 & 0xFFFF0000u) == want) &
                             ((v4 & 0xFFFF0000u) == want) & ((v5 & 0xFFFF0000u) == want) &
                             ((v6 & 0xFFFF0000u) == want) & ((v7 & 0xFFFF0000u) == want);
                    }
                    if (fp) ok &= (ld_a(fp) >= fneed);
                    if (__all(ok)) break;
                }
                if (t > 0) {
                    const int ab = er * AS + 2 * up;
                    *(unsigned*)&A[ab + p0] = (v0 & 0xFFFFu) | (v1 << 16);
                    *(unsigned*)&A[ab + p1] = (v2 & 0xFFFFu) | (v3 << 16);
                    *(unsigned*)&A[ab + p2] = (v4 & 0xFFFFu) | (v5 << 16);
                    *(unsigned*)&A[ab + p3] = (v6 & 0xFFFFu) | (v7 << 16);
                }
            }
            __syncthreads();                       // B1 (also drains t-1's global stores)
            if (tid == 0) st_a(FHown, (unsigned)t);   // h(0..t-1) now visible

            unsigned q0, q1, q2, q3;
            if (l > 0) {                           // zin(t) into regs; consumed after B2
                const unsigned* zp = zinL + (size_t)(t & 15) * 12800 + er * 800 + 4 * (s * 40 + up);
                q0 = ld_a(zp); q1 = ld_a(zp + 1); q2 = ld_a(zp + 2); q3 = ld_a(zp + 3);
            }

            floatx4 a0 = {0, 0, 0, 0}, a1 = {0, 0, 0, 0};
            #pragma unroll
            for (int kt = 0; kt < 13; ++kt) {
                bf16x8 a = *(const bf16x8*)(&A[aoff + kt * 32]);
                a0 = __builtin_amdgcn_mfma_f32_16x16x32_bf16(a, breg[0][kt], a0, 0, 0, 0);
                a1 = __builtin_amdgcn_mfma_f32_16x16x32_bf16(a, breg[1][kt], a1, 0, 0, 0);
            }
            #pragma unroll
            for (int ri = 0; ri < 4; ++ri) {
                Z[(zr + ri) * ZS + zc0] = a0[ri];
                Z[(zr + ri) * ZS + zc0 + 16] = a1[ri];
            }
            __syncthreads();                       // B2

            float4 za = *(const float4*)(&Z[er * ZS + 8 * up]);
            float4 zb4 = *(const float4*)(&Z[er * ZS + 8 * up + 4]);
            if (l > 0) {
                za.x += bf_lo(q0); za.y += bf_hi(q0); za.z += bf_lo(q1); za.w += bf_hi(q1);
                zb4.x += bf_lo(q2); zb4.y += bf_hi(q2); zb4.z += bf_lo(q3); zb4.w += bf_hi(q3);
            }
            float iv = sigm_(za.x + pi0 * c0);
            float fv = sigm_(za.y + pf0 * c0);
            float cn = fv * c0 + iv * tanh_(za.z);
            float ov = sigm_(za.w + po0 * cn);
            float h0 = ov * tanh_(cn);
            c0 = cn;
            iv = sigm_(zb4.x + pi1 * c1);
            fv = sigm_(zb4.y + pf1 * c1);
            cn = fv * c1 + iv * tanh_(zb4.z);
            ov = sigm_(zb4.w + po1 * cn);
            float h1 = ov * tanh_(cn);
            c1 = cn;
            unsigned packh = (unsigned)f2bf(h0) | ((unsigned)f2bf(h1) << 16);
            *(unsigned*)&A[er * AS + ug0] = packh;            // own h(t) -> LDS
            if (l == 0 && tid < 16 && t + 1 < TSTEPS)
                *(uint2*)(&A[tid * AS + 400]) = *(const uint2*)(xpack + ((size_t)(t + 1) * 64 + g * 16 + tid) * 4);
            __syncthreads();                       // B3

            // global stores AFTER the barrier: drain hides under next detect
            unsigned* hxs = hxL + (size_t)(t & 3) * 6400 + er * 400 + ug0;
            st_a(hxs, ((unsigned)t << 16) | (packh & 0xFFFFu));
            st_a(hxs + 1, ((unsigned)t << 16) | (packh >> 16));
            if (l < 2)
                st_a(ringL + (size_t)(t & 15) * 3200 + er * 200 + s * 40 + up, packh);
            else
                h2[(size_t)t * 12800 + (g * GB + er) * 200 + s * 40 + up] = packh;
        }
        __syncthreads();
        if (tid == 0) st_a(FHown, (unsigned)TSTEPS);
    } else {
        // ---------------- preGEMM block (TCH=2 steps per iter) ----------------
        const int p = bid - 60;
        const int lz = p / 20;               // feeds layer lz+1
        const int g = (p % 20) / 5;
        const int sp = p % 5;
        bf16x8 breg[2][13];
        #pragma unroll
        for (int n = 0; n < 2; ++n) {
            const unsigned short* bpp = Bpre + (size_t)lz * 1600 * KP
                + (size_t)(sp * CB + w * 32 + n * 16 + (lane & 15)) * KP + ((lane >> 4) << 3);
            #pragma unroll
            for (int kt = 0; kt < 13; ++kt) breg[n][kt] = *(const bf16x8*)(bpp + kt * 32);
        }
        const unsigned* ringS = hring + (size_t)(lz * NG + g) * RD * 3200;
        unsigned* zinD = zin + (size_t)(lz * NG + g) * RD * 12800;
        const unsigned* FHup = seqb + ((lz * NG + g) * NSL) * 16;
        const unsigned* FHdn = seqb + (((lz + 1) * NG + g) * NSL) * 16;
        unsigned* FZown = seqb + (60 + (lz * NG + g) * NSL + sp) * 16;
        __syncthreads();

        for (int c = 0; c < TSTEPS; c += 2) {
            {   // ballot poll: h availability + zin-ring backpressure
                const unsigned* fp = nullptr; unsigned need = 0;
                if (tid < NSL) { fp = FHup + tid * 16; need = (unsigned)(c + 2); }
                else if (tid < 2 * NSL) { fp = FHdn + (tid - NSL) * 16; need = (unsigned)(c > 14 ? c - 14 : 0); }
                bool ok = (fp == nullptr) || (ld_a(fp) >= need);
                while (!__all(ok)) { if (!ok) ok = ld_a(fp) >= need; }
            }
            __syncthreads();                       // B1 (drains prev chunk's zin stores)
            if (tid == 0 && c > 0) st_a(FZown, (unsigned)c);   // zin(0..c-1) visible

            for (int i = tid; i < 6400; i += 640) {   // stage h(c),h(c+1)
                int tc = i / 3200, j = i - tc * 3200;
                unsigned v = ld_a(ringS + (size_t)((c + tc) & 15) * 3200 + j);
                int r = j / 200, d = j - r * 200;
                *(unsigned*)&A[(tc * 16 + r) * AS + 2 * d] = v;
            }
            if (tid < 32) {
                int tc = tid >> 4, r = tid & 15;
                *(uint2*)(&A[(tc * 16 + r) * AS + 400]) =
                    *(const uint2*)(xpack + ((size_t)(c + tc) * 64 + g * 16 + r) * 4);
            }
            __syncthreads();                       // B2

            floatx4 a00 = {0,0,0,0}, a01 = {0,0,0,0}, a10 = {0,0,0,0}, a11 = {0,0,0,0};
            #pragma unroll
            for (int kt = 0; kt < 13; ++kt) {
                bf16x8 x0 = *(const bf16x8*)(&A[aoff + kt * 32]);
                bf16x8 x1 = *(const bf16x8*)(&A[aoff + 16 * AS + kt * 32]);
                a00 = __builtin_amdgcn_mfma_f32_16x16x32_bf16(x0, breg[0][kt], a00, 0, 0, 0);
                a01 = __builtin_amdgcn_mfma_f32_16x16x32_bf16(x0, breg[1][kt], a01, 0, 0, 0);
                a10 = __builtin_amdgcn_mfma_f32_16x16x32_bf16(x1, breg[0][kt], a10, 0, 0, 0);
                a11 = __builtin_amdgcn_mfma_f32_16x16x32_bf16(x1, breg[1][kt], a11, 0, 0, 0);
            }
            #pragma unroll
            for (int m = 0; m < 2; ++m) {
                #pragma unroll
                for (int ri = 0; ri < 4; ++ri) {
                    Z[(zr + ri) * ZS + zc0] = (m ? a10[ri] : a00[ri]);
                    Z[(zr + ri) * ZS + zc0 + 16] = (m ? a11[ri] : a01[ri]);
                }
                __syncthreads();                   // Z ready
                float4 za = *(const float4*)(&Z[er * ZS + 8 * up]);
                float4 zbv = *(const float4*)(&Z[er * ZS + 8 * up + 4]);
                unsigned* zg = zinD + (size_t)((c + m) & 15) * 12800 + er * 800 + sp * 160 + 4 * up;
                st_a(zg,     (unsigned)f2bf(za.x) | ((unsigned)f2bf(za.y) << 16));
                st_a(zg + 1, (unsigned)f2bf(za.z) | ((unsigned)f2bf(za.w) << 16));
                st_a(zg + 2, (unsigned)f2bf(zbv.x) | ((unsigned)f2bf(zbv.y) << 16));
                st_a(zg + 3, (unsigned)f2bf(zbv.z) | ((unsigned)f2bf(zbv.w) << 16));
                __syncthreads();                   // pack reads done before Z reuse
            }
        }
        __syncthreads();
        if (tid == 0) st_a(FZown, (unsigned)TSTEPS);
    }
}

// ---- MDN head ------------------------------------------------------------
__global__ __launch_bounds__(256)
void mdn_kernel(const unsigned short* __restrict__ h2,
                const unsigned short* __restrict__ Bm,
                float* __restrict__ out) {
    const int blk = blockIdx.x;
    const int b = blk / 25;
    const int t0 = (blk - b * 25) * 32;
    const int tid = threadIdx.x;
    const int lane = tid & 63;
    const int w = tid >> 6;
    const int m = w & 1, nh = w >> 1;

    __shared__ unsigned short A[32 * 424];
    __shared__ float Z[32 * 132];
    __shared__ float rmax[32], rinv[32];

    for (int i = tid; i < 32 * 424; i += 256) A[i] = 0;
    __syncthreads();
    for (int c = tid; c < 32 * 50; c += 256) {
        int r = c / 50, j = c - r * 50;
        *(bf16x8*)(&A[r * 424 + j * 8]) = *(const bf16x8*)(h2 + (size_t)(t0 + r) * 25600 + b * 400 + j * 8);
    }
    if (tid < 32) A[tid * 424 + 400] = 0x3F80u;
    __syncthreads();

    floatx4 acc[4] = {{0,0,0,0},{0,0,0,0},{0,0,0,0},{0,0,0,0}};
    const int aoff = (m * 16 + (lane & 15)) * 424 + ((lane >> 4) << 3);
    #pragma unroll
    for (int kt = 0; kt < 13; ++kt) {
        bf16x8 a = *(const bf16x8*)(&A[aoff + kt * 32]);
        #pragma unroll
        for (int n = 0; n < 4; ++n) {
            const unsigned short* bp = Bm + (size_t)((nh * 4 + n) * 16 + (lane & 15)) * KP
                                          + ((lane >> 4) << 3) + kt * 32;
            acc[n] = __builtin_amdgcn_mfma_f32_16x16x32_bf16(a, *(const bf16x8*)bp, acc[n], 0, 0, 0);
        }
    }
    #pragma unroll
    for (int n = 0; n < 4; ++n) {
        int zc = (nh * 4 + n) * 16 + (lane & 15);
        int zrow = m * 16 + ((lane >> 4) << 2);
        #pragma unroll
        for (int ri = 0; ri < 4; ++ri)
            Z[(zrow + ri) * 132 + zc] = acc[n][ri];
    }
    __syncthreads();
    if (tid < 32) {
        float mx = -1e30f;
        for (int j = 0; j < 20; ++j) mx = fmaxf(mx, Z[tid * 132 + j]);
        float sm = 0.f;
        for (int j = 0; j < 20; ++j) sm += __expf(Z[tid * 132 + j] - mx);
        rmax[tid] = mx;
        rinv[tid] = 1.f / sm;
    }
    __syncthreads();
    for (int idx = tid; idx < 32 * 121; idx += 256) {
        int r = idx / 121, jo = idx - r * 121;
        float v = Z[r * 132 + jo];
        float o;
        if (jo < 20) o = __expf(v - rmax[r]) * rinv[r];
        else if (jo < 60) o = v;
        else if (jo < 100) o = __expf(v);
        else if (jo < 120) o = tanh_(v);
        else o = sigm_(v);
        out[(size_t)(b * TSTEPS + t0 + r) * 121 + jo] = o;
    }
}

extern "C" void kernel_launch(void* const* d_in, const int* in_sizes, int n_in,
                              void* d_out, int out_size, void* d_ws, size_t ws_size,
                              hipStream_t stream) {
    const float* x = (const float*)d_in[0];
    const float* Wx[3] = {(const float*)d_in[1], (const float*)d_in[7], (const float*)d_in[13]};
    const float* Wh[3] = {(const float*)d_in[2], (const float*)d_in[8], (const float*)d_in[14]};
    const float* bb[3] = {(const float*)d_in[3], (const float*)d_in[9], (const float*)d_in[15]};
    Peeps pp;
    for (int l = 0; l < 3; ++l) {
        pp.pi[l] = (const float*)d_in[4 + 6 * l];
        pp.pf[l] = (const float*)d_in[5 + 6 * l];
        pp.po[l] = (const float*)d_in[6 + 6 * l];
    }
    const float* Wm = (const float*)d_in[19];
    const float* bm = (const float*)d_in[20];
    float* out = (float*)d_out;

    char* base = (char*)d_ws;
    size_t off = 0;
    auto alloc = [&](size_t bytes) -> void* {
        void* r = base + off;
        off = (off + bytes + 255) & ~(size_t)255;
        return r;
    };
    unsigned* seqb        = (unsigned*)alloc(1600 * sizeof(unsigned));              // 6.4 KB
    unsigned* hx          = (unsigned*)alloc((size_t)3 * NG * HXD * 6400 * 4);      // 1.23 MB
    unsigned* hring       = (unsigned*)alloc((size_t)3 * NG * RD * 3200 * 4);       // 2.46 MB
    unsigned* zin         = (unsigned*)alloc((size_t)2 * NG * RD * 12800 * 4);      // 6.55 MB
    unsigned short* Bp    = (unsigned short*)alloc((size_t)3 * 1600 * KP * 2);      // 4.0 MB
    unsigned short* Bpre  = (unsigned short*)alloc((size_t)2 * 1600 * KP * 2);      // 2.7 MB
    unsigned short* Bm    = (unsigned short*)alloc((size_t)128 * KP * 2);
    unsigned short* xpk   = (unsigned short*)alloc((size_t)TSTEPS * 64 * 4 * 2);
    unsigned short* h2    = (unsigned short*)alloc((size_t)TSTEPS * 64 * 400 * 2);  // 41 MB

    hipMemsetAsync(seqb, 0, 1600 * sizeof(unsigned), stream);
    hipMemsetAsync(hx, 0xAA, (size_t)3 * NG * HXD * 6400 * 4, stream);  // tags can't alias

    for (int l = 0; l < 3; ++l)
        pack_rec<<<2600, 256, 0, stream>>>(Wx[l], Wh[l], bb[l], Bp + (size_t)l * 1600 * KP, l == 0);
    pack_pre<<<2600, 256, 0, stream>>>(Wx[1], bb[1], Bpre);
    pack_pre<<<2600, 256, 0, stream>>>(Wx[2], bb[2], Bpre + (size_t)1600 * KP);
    pack_x<<<200, 256, 0, stream>>>(x, xpk);
    pack_mdn<<<208, 256, 0, stream>>>(Wm, bm, Bm);

    fused_scan<<<100, 640, 0, stream>>>(Bp, Bpre, xpk, hx, hring, zin, seqb,
                                        (unsigned*)h2, pp);

    mdn_kernel<<<1600, 256, 0, stream>>>(h2, Bm, out);
}